// Round 1
// baseline (48.544 us; speedup 1.0000x reference)
//
#include <hip/hip_runtime.h>

#define B_    8
#define L_    512
#define DIM_  256
#define INNER_ 512
#define M_ROWS (B_*L_)        // 4096

typedef __bf16 bf16x8 __attribute__((ext_vector_type(8)));
typedef float  fl4    __attribute__((ext_vector_type(4)));

typedef const __attribute__((address_space(1))) void gvoid;
typedef __attribute__((address_space(3))) void lvoid;

__device__ __forceinline__ void gl_lds16(const void* g, void* l) {
    __builtin_amdgcn_global_load_lds((gvoid*)g, (lvoid*)l, 16, 0, 0);
}

__device__ __forceinline__ unsigned short f2bf(float f) {
    unsigned int u = __float_as_uint(f);
    u = (u + 0x7fffu + ((u >> 16) & 1u)) >> 16;   // RNE
    return (unsigned short)u;
}
__device__ __forceinline__ float bf2f(unsigned short s) {
    return __uint_as_float(((unsigned int)s) << 16);
}

// ---------------------------------------------------------------- convert
__global__ __launch_bounds__(256) void convert_bf16(
    const float* __restrict__ x, const float* __restrict__ win,
    const float* __restrict__ wout,
    unsigned short* __restrict__ xb, unsigned short* __restrict__ winb,
    unsigned short* __restrict__ woutb)
{
    const int NX4 = (M_ROWS*DIM_) / 4;        // 262144
    const int NW4 = (2*INNER_*DIM_) / 4;      // 65536
    const int NO4 = (DIM_*INNER_) / 4;        // 32768
    int i4 = blockIdx.x * blockDim.x + threadIdx.x;
    const float* src; unsigned short* dst; int off;
    if (i4 < NX4)            { src = x;    dst = xb;    off = i4; }
    else if (i4 < NX4+NW4)   { src = win;  dst = winb;  off = i4 - NX4; }
    else if (i4 < NX4+NW4+NO4){ src = wout; dst = woutb; off = i4 - NX4 - NW4; }
    else return;
    float4 v = *(const float4*)&src[(size_t)off*4];
    ushort4 o;
    o.x = f2bf(v.x); o.y = f2bf(v.y); o.z = f2bf(v.z); o.w = f2bf(v.w);
    *(ushort4*)&dst[(size_t)off*4] = o;
}

// ---------------------------------------------------------------- gemm (bt: C[m,n] = sum_k A[m,k]*B[n,k])
template<int Ndim, int Kdim, bool OUT_BF16>
__global__ __launch_bounds__(256) void gemm_bt(
    const unsigned short* __restrict__ A,
    const unsigned short* __restrict__ Bm,
    void* __restrict__ C)
{
    constexpr int BM = 128, BN = 128, BK = 32;
    __shared__ __align__(16) unsigned short As[BM*BK];
    __shared__ __align__(16) unsigned short Bs[BN*BK];
    const int tid  = threadIdx.x;
    const int wave = tid >> 6, lane = tid & 63;
    const int wr = (wave >> 1) << 6;          // wave row origin in tile
    const int wc = (wave & 1) << 6;           // wave col origin in tile
    const int rowA0 = blockIdx.x * BM;
    const int rowB0 = blockIdx.y * BN;
    fl4 acc[4][4] = {};

    for (int kt = 0; kt < Kdim; kt += BK) {
        __syncthreads();                       // LDS safe to overwrite
        #pragma unroll
        for (int i = 0; i < 2; ++i) {
            const int chunk = wave + i*4;      // 0..7, 1KB each
            const int lbyte = chunk*1024 + lane*16;
            const int r  = lbyte >> 6;         // row in tile (64B per row)
            const int ke = ((lbyte & 63) >> 1);// element offset in row
            gl_lds16(A  + (size_t)(rowA0 + r)*Kdim + kt + ke, (char*)As + chunk*1024);
            gl_lds16(Bm + (size_t)(rowB0 + r)*Kdim + kt + ke, (char*)Bs + chunk*1024);
        }
        __syncthreads();                       // loads landed (vmcnt(0) drained)

        bf16x8 af[4], bfr[4];
        #pragma unroll
        for (int m = 0; m < 4; ++m)
            af[m] = *(const bf16x8*)&As[(wr + m*16 + (lane & 15))*BK + (lane >> 4)*8];
        #pragma unroll
        for (int n = 0; n < 4; ++n)
            bfr[n] = *(const bf16x8*)&Bs[(wc + n*16 + (lane & 15))*BK + (lane >> 4)*8];
        #pragma unroll
        for (int m = 0; m < 4; ++m)
            #pragma unroll
            for (int n = 0; n < 4; ++n)
                acc[m][n] = __builtin_amdgcn_mfma_f32_16x16x32_bf16(af[m], bfr[n], acc[m][n], 0, 0, 0);
    }

    #pragma unroll
    for (int m = 0; m < 4; ++m)
        #pragma unroll
        for (int n = 0; n < 4; ++n)
            #pragma unroll
            for (int r = 0; r < 4; ++r) {
                const int row = rowA0 + wr + m*16 + (lane >> 4)*4 + r;
                const int col = rowB0 + wc + n*16 + (lane & 15);
                const float v = acc[m][n][r];
                if constexpr (OUT_BF16)
                    ((unsigned short*)C)[(size_t)row*Ndim + col] = f2bf(v);
                else
                    ((float*)C)[(size_t)row*Ndim + col] = v;
            }
}

// ---------------------------------------------------------------- conv + scan + gate
// xp: [B*L][1024] bf16 (u = cols 0..511, g = cols 512..1023) -> y: [B*L][512] bf16
// block: 512 threads = 64 channels x 8 chunks of 64 timesteps. grid: B*8 (8 channel-blocks).
__global__ __launch_bounds__(512) void scan_gate(
    const unsigned short* __restrict__ xp,
    const float* __restrict__ sdecay, const float* __restrict__ sscale,
    const float* __restrict__ convw,
    unsigned short* __restrict__ y)
{
    const int b    = blockIdx.x >> 3;
    const int cb   = blockIdx.x & 7;
    const int lane = threadIdx.x & 63;
    const int j    = threadIdx.x >> 6;         // chunk id 0..7
    const int c    = cb*64 + lane;

    const float draw = 1.0f / (1.0f + __expf(-sdecay[c]));
    const float deff = fmaxf(draw, 1e-6f);     // matches exp(log(max(d,1e-6)))
    const float ins  = (1.0f - draw) * sscale[c];
    const float w0 = convw[c*3+0], w1 = convw[c*3+1], w2 = convw[c*3+2];

    const int t0 = j*64;
    const size_t rowbase = ((size_t)b*L_ + t0)*1024 + c;

    float h1 = 0.f, h2 = 0.f;                   // conv history u[t0-1], u[t0-2]
    if (t0 >= 1) h1 = bf2f(xp[rowbase - 1024]);
    if (t0 >= 2) h2 = bf2f(xp[rowbase - 2048]);

    // ---- phase 1: local scan (zero init) -> carry
    float um1 = h1, um2 = h2, s = 0.f;
    for (int tb = 0; tb < 64; tb += 8) {
        float uu[8];
        #pragma unroll
        for (int i = 0; i < 8; ++i) uu[i] = bf2f(xp[rowbase + (size_t)(tb+i)*1024]);
        #pragma unroll
        for (int i = 0; i < 8; ++i) {
            float uc = fmaf(w2, uu[i], fmaf(w1, um1, w0*um2));
            um2 = um1; um1 = uu[i];
            s = fmaf(deff, s, ins*uc);
        }
    }

    __shared__ float carry[8][64];
    carry[j][lane] = s;
    __syncthreads();

    const float dp = __powf(deff, 64.0f);
    float s0 = 0.f;
    for (int i = 0; i < j; ++i) s0 = fmaf(s0, dp, carry[i][lane]);

    // ---- phase 2: rescan with correct init, gate, store
    um1 = h1; um2 = h2; s = s0;
    for (int tb = 0; tb < 64; tb += 8) {
        float uu[8], gg[8];
        #pragma unroll
        for (int i = 0; i < 8; ++i) {
            uu[i] = bf2f(xp[rowbase + (size_t)(tb+i)*1024]);
            gg[i] = bf2f(xp[rowbase + (size_t)(tb+i)*1024 + 512]);
        }
        #pragma unroll
        for (int i = 0; i < 8; ++i) {
            float uc = fmaf(w2, uu[i], fmaf(w1, um1, w0*um2));
            um2 = um1; um1 = uu[i];
            s = fmaf(deff, s, ins*uc);
            float gate = 1.0f / (1.0f + __expf(-gg[i]));
            y[((size_t)b*L_ + t0 + tb + i)*INNER_ + c] = f2bf(s * gate);
        }
    }
}

// ---------------------------------------------------------------- rmsnorm (in-place on d_out)
__global__ __launch_bounds__(256) void rmsnorm_k(float* __restrict__ io,
                                                 const float* __restrict__ w)
{
    const int row  = blockIdx.x*4 + (threadIdx.x >> 6);
    const int lane = threadIdx.x & 63;
    float4 v = *(const float4*)&io[(size_t)row*DIM_ + lane*4];
    float ss = v.x*v.x + v.y*v.y + v.z*v.z + v.w*v.w;
    #pragma unroll
    for (int off = 32; off > 0; off >>= 1) ss += __shfl_xor(ss, off, 64);
    const float r = rsqrtf(ss * (1.0f/DIM_) + 1e-6f);
    const float4 wv = *(const float4*)&w[lane*4];
    float4 o;
    o.x = v.x*r*wv.x; o.y = v.y*r*wv.y; o.z = v.z*r*wv.z; o.w = v.w*r*wv.w;
    *(float4*)&io[(size_t)row*DIM_ + lane*4] = o;
}

// ---------------------------------------------------------------- launch
extern "C" void kernel_launch(void* const* d_in, const int* in_sizes, int n_in,
                              void* d_out, int out_size, void* d_ws, size_t ws_size,
                              hipStream_t stream)
{
    const float* x      = (const float*)d_in[0];
    const float* Win    = (const float*)d_in[1];
    const float* convw  = (const float*)d_in[2];
    const float* sdecay = (const float*)d_in[3];
    const float* sscale = (const float*)d_in[4];
    const float* Wout   = (const float*)d_in[5];
    const float* normw  = (const float*)d_in[6];
    float* out = (float*)d_out;

    char* ws = (char*)d_ws;
    unsigned short* xb    = (unsigned short*)(ws);                       // 2 MB
    unsigned short* winb  = (unsigned short*)(ws + (2u<<20));            // 0.5 MB
    unsigned short* woutb = (unsigned short*)(ws + (2u<<20) + (512u<<10)); // 0.25 MB
    unsigned short* xp    = (unsigned short*)(ws + (3u<<20));            // 8 MB
    unsigned short* yb    = (unsigned short*)(ws + (11u<<20));           // 4 MB

    convert_bf16<<<1408, 256, 0, stream>>>(x, Win, Wout, xb, winb, woutb);
    gemm_bt<2*INNER_, DIM_, true><<<dim3(M_ROWS/128, (2*INNER_)/128), 256, 0, stream>>>(xb, winb, xp);
    scan_gate<<<B_*8, 512, 0, stream>>>(xp, sdecay, sscale, convw, yb);
    gemm_bt<DIM_, INNER_, false><<<dim3(M_ROWS/128, DIM_/128), 256, 0, stream>>>(yb, woutb, out);
    rmsnorm_k<<<M_ROWS/4, 256, 0, stream>>>(out, normw);
}

// Round 2
// 46.287 us; speedup vs baseline: 1.0488x; 1.0488x over previous
//
#include <hip/hip_runtime.h>

#define B_    8
#define L_    512
#define DIM_  256
#define INNER_ 512
#define M_ROWS (B_*L_)        // 4096

typedef __bf16 bf16x8 __attribute__((ext_vector_type(8)));
typedef float  fl4    __attribute__((ext_vector_type(4)));

typedef const __attribute__((address_space(1))) void gvoid;
typedef __attribute__((address_space(3))) void lvoid;

__device__ __forceinline__ void gl_lds16(const void* g, void* l) {
    __builtin_amdgcn_global_load_lds((gvoid*)g, (lvoid*)l, 16, 0, 0);
}

__device__ __forceinline__ unsigned short f2bf(float f) {
    unsigned int u = __float_as_uint(f);
    u = (u + 0x7fffu + ((u >> 16) & 1u)) >> 16;   // RNE
    return (unsigned short)u;
}
__device__ __forceinline__ float bf2f(unsigned short s) {
    return __uint_as_float(((unsigned int)s) << 16);
}

// ---------------------------------------------------------------- convert
__global__ __launch_bounds__(256) void convert_bf16(
    const float* __restrict__ x, const float* __restrict__ win,
    const float* __restrict__ wout,
    unsigned short* __restrict__ xb, unsigned short* __restrict__ winb,
    unsigned short* __restrict__ woutb)
{
    const int NX4 = (M_ROWS*DIM_) / 4;        // 262144
    const int NW4 = (2*INNER_*DIM_) / 4;      // 65536
    const int NO4 = (DIM_*INNER_) / 4;        // 32768
    int i4 = blockIdx.x * blockDim.x + threadIdx.x;
    const float* src; unsigned short* dst; int off;
    if (i4 < NX4)            { src = x;    dst = xb;    off = i4; }
    else if (i4 < NX4+NW4)   { src = win;  dst = winb;  off = i4 - NX4; }
    else if (i4 < NX4+NW4+NO4){ src = wout; dst = woutb; off = i4 - NX4 - NW4; }
    else return;
    float4 v = *(const float4*)&src[(size_t)off*4];
    ushort4 o;
    o.x = f2bf(v.x); o.y = f2bf(v.y); o.z = f2bf(v.z); o.w = f2bf(v.w);
    *(ushort4*)&dst[(size_t)off*4] = o;
}

// ---------------------------------------------------------------- gemm (bt: C[m,n] = sum_k A[m,k]*B[n,k])
// OUT_MODE: 0 = f32, 1 = bf16, 2 = f32 + fused RMSNorm over the row (requires BN == Ndim == DIM_)
template<int BM, int BN, int WGR, int WGC, int Ndim, int Kdim, int OUT_MODE>
__global__ __launch_bounds__(256) void gemm_bt(
    const unsigned short* __restrict__ A,
    const unsigned short* __restrict__ Bm,
    void* __restrict__ C,
    const float* __restrict__ normw)
{
    constexpr int BK = 32;
    constexpr int WM = BM / WGR, WN = BN / WGC;  // per-wave output tile
    constexpr int AM = WM / 16,  AN = WN / 16;   // acc fragment grid
    constexpr int ACH = BM / 16;                 // A chunks of 1KB (row = 64B)
    constexpr int NCH = (BM + BN) / 16;
    __shared__ __align__(16) unsigned short As[BM*BK];
    __shared__ __align__(16) unsigned short Bs[BN*BK];
    __shared__ float ssp[(OUT_MODE == 2) ? BM*WGC : 1];

    const int tid  = threadIdx.x;
    const int wave = tid >> 6, lane = tid & 63;
    const int wr = (wave / WGC) * WM;
    const int wc = (wave % WGC) * WN;
    const int rowA0 = blockIdx.x * BM;
    const int rowB0 = blockIdx.y * BN;
    fl4 acc[AM][AN] = {};

    for (int kt = 0; kt < Kdim; kt += BK) {
        __syncthreads();                       // LDS safe to overwrite
        #pragma unroll
        for (int ch = wave; ch < NCH; ch += 4) {
            const int rl = (lane >> 2);        // 0..15 row within chunk
            const int ke = (lane & 3) * 8;     // element offset within 32-elem row
            if (ch < ACH) {
                const int r = ch*16 + rl;
                gl_lds16(A + (size_t)(rowA0 + r)*Kdim + kt + ke, (char*)As + ch*1024);
            } else {
                const int r = (ch - ACH)*16 + rl;
                gl_lds16(Bm + (size_t)(rowB0 + r)*Kdim + kt + ke, (char*)Bs + (ch - ACH)*1024);
            }
        }
        __syncthreads();                       // loads landed (vmcnt(0) drained)

        bf16x8 af[AM], bfr[AN];
        #pragma unroll
        for (int m = 0; m < AM; ++m)
            af[m] = *(const bf16x8*)&As[(wr + m*16 + (lane & 15))*BK + (lane >> 4)*8];
        #pragma unroll
        for (int n = 0; n < AN; ++n)
            bfr[n] = *(const bf16x8*)&Bs[(wc + n*16 + (lane & 15))*BK + (lane >> 4)*8];
        #pragma unroll
        for (int m = 0; m < AM; ++m)
            #pragma unroll
            for (int n = 0; n < AN; ++n)
                acc[m][n] = __builtin_amdgcn_mfma_f32_16x16x32_bf16(af[m], bfr[n], acc[m][n], 0, 0, 0);
    }

    if constexpr (OUT_MODE == 2) {
        // fused RMSNorm: block holds full rows (BN == Ndim)
        #pragma unroll
        for (int m = 0; m < AM; ++m)
            #pragma unroll
            for (int r = 0; r < 4; ++r) {
                float t = 0.f;
                #pragma unroll
                for (int n = 0; n < AN; ++n) { float v = acc[m][n][r]; t = fmaf(v, v, t); }
                t += __shfl_xor(t, 1, 64); t += __shfl_xor(t, 2, 64);
                t += __shfl_xor(t, 4, 64); t += __shfl_xor(t, 8, 64);
                if ((lane & 15) == 0)
                    ssp[(wr + m*16 + (lane >> 4)*4 + r)*WGC + wave] = t;
            }
        __syncthreads();
        float nwv[AN];
        #pragma unroll
        for (int n = 0; n < AN; ++n) nwv[n] = normw[wc + n*16 + (lane & 15)];
        #pragma unroll
        for (int m = 0; m < AM; ++m)
            #pragma unroll
            for (int r = 0; r < 4; ++r) {
                const int rl = wr + m*16 + (lane >> 4)*4 + r;
                float ss = 0.f;
                #pragma unroll
                for (int w = 0; w < WGC; ++w) ss += ssp[rl*WGC + w];
                const float rf = rsqrtf(ss * (1.0f/Ndim) + 1e-6f);
                #pragma unroll
                for (int n = 0; n < AN; ++n) {
                    const int col = wc + n*16 + (lane & 15);
                    ((float*)C)[(size_t)(rowA0 + rl)*Ndim + col] = acc[m][n][r] * rf * nwv[n];
                }
            }
    } else {
        #pragma unroll
        for (int m = 0; m < AM; ++m)
            #pragma unroll
            for (int n = 0; n < AN; ++n)
                #pragma unroll
                for (int r = 0; r < 4; ++r) {
                    const int row = rowA0 + wr + m*16 + (lane >> 4)*4 + r;
                    const int col = rowB0 + wc + n*16 + (lane & 15);
                    const float v = acc[m][n][r];
                    if constexpr (OUT_MODE == 1)
                        ((unsigned short*)C)[(size_t)row*Ndim + col] = f2bf(v);
                    else
                        ((float*)C)[(size_t)row*Ndim + col] = v;
                }
    }
}

// ---------------------------------------------------------------- conv + scan + gate (single pass, analytic carry)
// xp: [B*L][1024] bf16 (u = cols 0..511, g = 512..1023) -> y: [B*L][512] bf16
// block: 512 threads = 16 channels x 32 chunks of 16 timesteps. grid: B * 32 channel-blocks.
__global__ __launch_bounds__(512) void scan_gate(
    const unsigned short* __restrict__ xp,
    const float* __restrict__ sdecay, const float* __restrict__ sscale,
    const float* __restrict__ convw,
    unsigned short* __restrict__ y)
{
    const int b    = blockIdx.x >> 5;
    const int cb   = blockIdx.x & 31;
    const int c_lo = threadIdx.x & 15;
    const int j    = threadIdx.x >> 4;          // chunk id 0..31
    const int c    = cb*16 + c_lo;

    const float draw = 1.0f / (1.0f + __expf(-sdecay[c]));
    const float deff = fmaxf(draw, 1e-6f);      // matches exp(log(max(d,1e-6)))
    const float ins  = (1.0f - draw) * sscale[c];
    const float w0 = convw[c*3+0], w1 = convw[c*3+1], w2 = convw[c*3+2];

    const int t0 = j*16;
    const size_t rowbase = ((size_t)b*L_ + t0)*1024 + c;

    float h1 = 0.f, h2 = 0.f;                   // conv history u[t0-1], u[t0-2]
    if (t0 >= 1) h1 = bf2f(xp[rowbase - 1024]);
    if (t0 >= 2) h2 = bf2f(xp[rowbase - 2048]);

    // single pass: local scan (zero init), stash locals + gates in regs
    float sloc[16], gr[16];
    {
        float um1 = h1, um2 = h2, s = 0.f;
        #pragma unroll
        for (int i = 0; i < 16; ++i) {
            const float u = bf2f(xp[rowbase + (size_t)i*1024]);
            gr[i] = bf2f(xp[rowbase + (size_t)i*1024 + 512]);
            const float uc = fmaf(w2, u, fmaf(w1, um1, w0*um2));
            um2 = um1; um1 = u;
            s = fmaf(deff, s, ins*uc);
            sloc[i] = s;
        }
        __shared__ float carry[32][16];
        carry[j][c_lo] = s;
        __syncthreads();
        const float dp16 = __powf(deff, 16.0f);
        float s0 = 0.f;
        for (int i = 0; i < j; ++i) s0 = fmaf(s0, dp16, carry[i][c_lo]);
        // apply carry analytically: s[t0+i] = sloc[i] + s0 * deff^(i+1)
        float pw = 1.0f;
        #pragma unroll
        for (int i = 0; i < 16; ++i) {
            pw *= deff;
            const float sv   = fmaf(s0, pw, sloc[i]);
            const float gate = 1.0f / (1.0f + __expf(-gr[i]));
            y[((size_t)b*L_ + t0 + i)*INNER_ + c] = f2bf(sv * gate);
        }
    }
}

// ---------------------------------------------------------------- launch
extern "C" void kernel_launch(void* const* d_in, const int* in_sizes, int n_in,
                              void* d_out, int out_size, void* d_ws, size_t ws_size,
                              hipStream_t stream)
{
    const float* x      = (const float*)d_in[0];
    const float* Win    = (const float*)d_in[1];
    const float* convw  = (const float*)d_in[2];
    const float* sdecay = (const float*)d_in[3];
    const float* sscale = (const float*)d_in[4];
    const float* Wout   = (const float*)d_in[5];
    const float* normw  = (const float*)d_in[6];
    float* out = (float*)d_out;

    char* ws = (char*)d_ws;
    unsigned short* xb    = (unsigned short*)(ws);                         // 2 MB
    unsigned short* winb  = (unsigned short*)(ws + (2u<<20));              // 0.5 MB
    unsigned short* woutb = (unsigned short*)(ws + (2u<<20) + (512u<<10)); // 0.25 MB
    unsigned short* xp    = (unsigned short*)(ws + (3u<<20));              // 8 MB
    unsigned short* yb    = (unsigned short*)(ws + (11u<<20));             // 4 MB

    convert_bf16<<<1408, 256, 0, stream>>>(x, Win, Wout, xb, winb, woutb);
    // GEMM1: [4096x256] x [1024x256]^T -> bf16 xp, tiles 128x64, grid 512 (2 blocks/CU)
    gemm_bt<128, 64, 2, 2, 2*INNER_, DIM_, 1>
        <<<dim3(M_ROWS/128, (2*INNER_)/64), 256, 0, stream>>>(xb, winb, xp, nullptr);
    scan_gate<<<B_*32, 512, 0, stream>>>(xp, sdecay, sscale, convw, yb);
    // GEMM2 + fused RMSNorm: [4096x512] x [256x512]^T -> f32 out, tiles 64x256, grid 64
    gemm_bt<64, 256, 1, 4, DIM_, INNER_, 2>
        <<<dim3(M_ROWS/64, 1), 256, 0, stream>>>(yb, woutb, out, normw);
}